// Round 14
// baseline (3206.371 us; speedup 1.0000x reference)
//
#include <hip/hip_runtime.h>
#include <stdint.h>

// SUBNET_15290083574166: encoder MLP -> 256-step recurrent f MLP -> output h MLP
// B=4096, T=256, NX=128, NU=16, NY=16, NB=NA=32, H=256
//
// Precision (VERIFIED r4-r13, absmax 0.0625 vs thr 0.24): f16 hi/lo pairs
// (2^-22) on all recurrence operands, 2-accum (hi + lo*2^-11); encoder bf16
// pairs; hnet xf-pair x f16-single. DO NOT change the numerics.
//
// r14 (bit-identical): barrier-1 eliminated. The u_t fragment is built
// per-lane in registers (g<2 lanes load ufut in exact fragment layout;
// g>=2 is the zero pad) instead of a LDS round-trip, so phase0 disappears:
// 5 barriers/step (was 6). xu shrinks to [16][136]; xf store moved to step
// top (reads cols 0..127, stable since prev state-write barrier), overlapping
// G1. u double-buffered in 8 regs (g<2 only) - r13 proved small reg adds
// don't trip the 128-VGPR cliff at this 512-thread shape.

typedef __attribute__((ext_vector_type(8))) short s8v;      // 8 bf16 bits
typedef __attribute__((ext_vector_type(8))) _Float16 h8v;   // 8 f16
typedef __attribute__((ext_vector_type(4))) float f4v;

__device__ __forceinline__ f4v mfma16(s8v a, s8v b, f4v c) {
  return __builtin_amdgcn_mfma_f32_16x16x32_bf16(a, b, c, 0, 0, 0);
}
__device__ __forceinline__ f4v mfmaH(h8v a, h8v b, f4v c) {
  return __builtin_amdgcn_mfma_f32_16x16x32_f16(a, b, c, 0, 0, 0);
}
__device__ __forceinline__ f4v zero4() { return (f4v){0.f, 0.f, 0.f, 0.f}; }
__device__ __forceinline__ h8v zeroh8() {
  h8v z;
#pragma unroll
  for (int q = 0; q < 8; ++q) z[q] = (_Float16)0.f;
  return z;
}

__device__ __forceinline__ unsigned short f2b(float x) {  // f32->bf16 RNE
  unsigned int u = __builtin_bit_cast(unsigned int, x);
  u += 0x7fffu + ((u >> 16) & 1u);
  return (unsigned short)(u >> 16);
}
__device__ __forceinline__ float b2f(unsigned short h) {
  return __builtin_bit_cast(float, (unsigned int)h << 16);
}
__device__ __forceinline__ unsigned short f2h(float x) {
  return __builtin_bit_cast(unsigned short, (_Float16)x);
}
__device__ __forceinline__ float h2f(unsigned short h) {
  return (float)__builtin_bit_cast(_Float16, h);
}

__device__ __forceinline__ float tanhf_fast(float x) {
  x = fminf(15.f, fmaxf(-15.f, x));
  float e = __expf(2.f * x);
  return (e - 1.f) / (e + 1.f);
}

// ---------------- weight swizzle: fp32 [K][N] -> fragment order ---------------
// frag: idx(nt,kk,lane,j) = ((nt*KK + kk)*64 + lane)*8 + j
//   holds W[kk*32 + (lane>>4)*8 + j][nt*16 + (lane&15)]  (zero-pad k>=K)
// mode 0: bf16 hi at dst[dhi+local], bf16 lo at dst[dlo+local]
// mode 3: f16 hi at dst[dhi+local], f16((v-hi)*2048) at dst[dlo+local]
// mode 1: f16 at dst[dhi+local]
struct SwzDesc { const float* src; long woff; long dhi; long dlo; int K; int Kp; int N; int mode; };
struct SwzTable { SwzDesc d[12]; long tot_work; };

__global__ void swz_kernel(SwzTable tbl, unsigned short* __restrict__ dst) {
  long gid = (long)blockIdx.x * 256 + threadIdx.x;
  if (gid >= tbl.tot_work) return;
  int i = 11;
  while (i > 0 && gid < tbl.d[i].woff) --i;
  const SwzDesc m = tbl.d[i];
  long local = gid - m.woff;
  int j = (int)(local & 7);
  int lane = (int)((local >> 3) & 63);
  long rem = local >> 9;
  int KK = m.Kp >> 5;
  int kk = (int)(rem % KK);
  int nt = (int)(rem / KK);
  int k = kk * 32 + (lane >> 4) * 8 + j;
  int n = nt * 16 + (lane & 15);
  float v = (k < m.K) ? m.src[(long)k * m.N + n] : 0.f;
  if (m.mode == 0) {
    unsigned short hi = f2b(v);
    dst[m.dhi + local] = hi;
    dst[m.dlo + local] = f2b(v - b2f(hi));
  } else if (m.mode == 3) {
    _Float16 hi = (_Float16)v;
    dst[m.dhi + local] = __builtin_bit_cast(unsigned short, hi);
    dst[m.dlo + local] = f2h((v - (float)hi) * 2048.f);
  } else {
    dst[m.dhi + local] = f2h(v);
  }
}

// ---------------- encoder (bf16 hi/lo 3-term, one-shot) ----------------------
__global__ __launch_bounds__(512, 2)
void enc_kernel(const float* __restrict__ upast, const float* __restrict__ ypast,
                const unsigned short* __restrict__ W1h, const unsigned short* __restrict__ W1l,
                const unsigned short* __restrict__ W2h, const unsigned short* __restrict__ W2l,
                const unsigned short* __restrict__ W3h, const unsigned short* __restrict__ W3l,
                const unsigned short* __restrict__ rWh, const unsigned short* __restrict__ rWl,
                const float* __restrict__ b1, const float* __restrict__ b2,
                const float* __restrict__ b3, const float* __restrict__ rb,
                float* __restrict__ xstate) {
  __shared__ __align__(16) unsigned short h1h[16][264], h1l[16][264];
  __shared__ __align__(16) unsigned short h2h[16][264], h2l[16][264];
  const int tid = threadIdx.x;
  const int w = tid >> 6, l = tid & 63;
  const int c = l & 15, g = l >> 4;
  const int b0 = blockIdx.x << 4;
  const long zrow = (long)(b0 + c) * 512;

  f4v a0 = zero4(), a1 = zero4();
  for (int kk = 0; kk < 32; ++kk) {
    const int cb = kk * 32 + g * 8;
    const float* zp = (cb < 512) ? (upast + zrow + cb) : (ypast + zrow + (cb - 512));
    float4 z0 = *(const float4*)zp;
    float4 z1 = *(const float4*)(zp + 4);
    float zz[8] = {z0.x, z0.y, z0.z, z0.w, z1.x, z1.y, z1.z, z1.w};
    s8v ah, al;
#pragma unroll
    for (int q = 0; q < 8; ++q) {
      unsigned short hi = f2b(zz[q]);
      ah[q] = (short)hi; al[q] = (short)f2b(zz[q] - b2f(hi));
    }
#pragma unroll
    for (int ct = 0; ct < 2; ++ct) {
      s8v bh = *(const s8v*)(W1h + (((long)(2 * w + ct) * 32 + kk) * 64 + l) * 8);
      s8v bl = *(const s8v*)(W1l + (((long)(2 * w + ct) * 32 + kk) * 64 + l) * 8);
      f4v& acc = ct ? a1 : a0;
      acc = mfma16(ah, bh, acc);
      acc = mfma16(al, bh, acc);
      acc = mfma16(ah, bl, acc);
    }
  }
  {
    const float bbA = b1[(2 * w + 0) * 16 + c], bbB = b1[(2 * w + 1) * 16 + c];
#pragma unroll
    for (int j = 0; j < 4; ++j) {
      float tA = tanhf_fast(a0[j] + bbA), tB = tanhf_fast(a1[j] + bbB);
      unsigned short hA = f2b(tA), hB = f2b(tB);
      h1h[g * 4 + j][(2 * w + 0) * 16 + c] = hA;
      h1l[g * 4 + j][(2 * w + 0) * 16 + c] = f2b(tA - b2f(hA));
      h1h[g * 4 + j][(2 * w + 1) * 16 + c] = hB;
      h1l[g * 4 + j][(2 * w + 1) * 16 + c] = f2b(tB - b2f(hB));
    }
  }
  __syncthreads();
  a0 = zero4(); a1 = zero4();
#pragma unroll
  for (int kk = 0; kk < 8; ++kk) {
    s8v ah = *(const s8v*)(&h1h[c][kk * 32 + g * 8]);
    s8v al = *(const s8v*)(&h1l[c][kk * 32 + g * 8]);
#pragma unroll
    for (int ct = 0; ct < 2; ++ct) {
      s8v bh = *(const s8v*)(W2h + (((long)(2 * w + ct) * 8 + kk) * 64 + l) * 8);
      s8v bl = *(const s8v*)(W2l + (((long)(2 * w + ct) * 8 + kk) * 64 + l) * 8);
      f4v& acc = ct ? a1 : a0;
      acc = mfma16(ah, bh, acc);
      acc = mfma16(al, bh, acc);
      acc = mfma16(ah, bl, acc);
    }
  }
  {
    const float bbA = b2[(2 * w + 0) * 16 + c], bbB = b2[(2 * w + 1) * 16 + c];
#pragma unroll
    for (int j = 0; j < 4; ++j) {
      float tA = tanhf_fast(a0[j] + bbA), tB = tanhf_fast(a1[j] + bbB);
      unsigned short hA = f2b(tA), hB = f2b(tB);
      h2h[g * 4 + j][(2 * w + 0) * 16 + c] = hA;
      h2l[g * 4 + j][(2 * w + 0) * 16 + c] = f2b(tA - b2f(hA));
      h2h[g * 4 + j][(2 * w + 1) * 16 + c] = hB;
      h2l[g * 4 + j][(2 * w + 1) * 16 + c] = f2b(tB - b2f(hB));
    }
  }
  __syncthreads();
  f4v ac = zero4();
#pragma unroll
  for (int kk = 0; kk < 8; ++kk) {
    s8v ah = *(const s8v*)(&h2h[c][kk * 32 + g * 8]);
    s8v al = *(const s8v*)(&h2l[c][kk * 32 + g * 8]);
    s8v bh = *(const s8v*)(W3h + (((long)w * 8 + kk) * 64 + l) * 8);
    s8v bl = *(const s8v*)(W3l + (((long)w * 8 + kk) * 64 + l) * 8);
    ac = mfma16(ah, bh, ac);
    ac = mfma16(al, bh, ac);
    ac = mfma16(ah, bl, ac);
  }
  for (int kk = 0; kk < 32; ++kk) {
    const int cb = kk * 32 + g * 8;
    const float* zp = (cb < 512) ? (upast + zrow + cb) : (ypast + zrow + (cb - 512));
    float4 z0 = *(const float4*)zp;
    float4 z1 = *(const float4*)(zp + 4);
    float zz[8] = {z0.x, z0.y, z0.z, z0.w, z1.x, z1.y, z1.z, z1.w};
    s8v ah, al;
#pragma unroll
    for (int q = 0; q < 8; ++q) {
      unsigned short hi = f2b(zz[q]);
      ah[q] = (short)hi; al[q] = (short)f2b(zz[q] - b2f(hi));
    }
    s8v bh = *(const s8v*)(rWh + (((long)w * 32 + kk) * 64 + l) * 8);
    s8v bl = *(const s8v*)(rWl + (((long)w * 32 + kk) * 64 + l) * 8);
    ac = mfma16(ah, bh, ac);
    ac = mfma16(al, bh, ac);
    ac = mfma16(ah, bl, ac);
  }
  {
    const float bias = b3[w * 16 + c] + rb[w * 16 + c];
#pragma unroll
    for (int j = 0; j < 4; ++j)
      xstate[(long)(b0 + g * 4 + j) * 128 + w * 16 + c] = ac[j] + bias;
  }
}

// ---------------- recurrence (f16 pairs, u-in-frag-regs, 5 barriers) ---------
// regs persistent (184): W1 pair 80, W2hi 64, rW pair 40. LDS: W3 pair 128KB +
// activations ~25KB. W2lo streamed from L2 (ct0 preload, ct1 in G1 tail).
__global__ __launch_bounds__(512, 2)
void recur_kernel(const float* __restrict__ ufut,
                  const unsigned short* __restrict__ W1h, const unsigned short* __restrict__ W1l,
                  const unsigned short* __restrict__ W2h, const unsigned short* __restrict__ W2l,
                  const unsigned short* __restrict__ W3h, const unsigned short* __restrict__ W3l,
                  const unsigned short* __restrict__ rWh, const unsigned short* __restrict__ rWl,
                  const float* __restrict__ b1, const float* __restrict__ b2,
                  const float* __restrict__ b3, const float* __restrict__ rb,
                  float* __restrict__ xstate,
                  unsigned short* __restrict__ xfh, unsigned short* __restrict__ xfl,
                  int t0, int len) {
  __shared__ __align__(16) unsigned short xu_h[16][136], xu_l[16][136];  // cols 0..127
  __shared__ __align__(16) unsigned short hh[16][264], hl[16][264];
  __shared__ __align__(16) unsigned short w3h_l[32768];   // W3 hi, full
  __shared__ __align__(16) unsigned short w3l_l[32768];   // W3 lo, full
  const int tid = threadIdx.x;
  const int w = tid >> 6, l = tid & 63;
  const int c = l & 15, g = l >> 4;
  const int b0 = blockIdx.x << 4;

  // persistent register fragments (f16)
  h8v w1h_r[2][5], w1l_r[2][5], w2h_r[2][8], rwh_r[5], rwl_r[5];
#pragma unroll
  for (int ct = 0; ct < 2; ++ct) {
#pragma unroll
    for (int kk = 0; kk < 5; ++kk) {
      w1h_r[ct][kk] = *(const h8v*)(W1h + (((long)(2 * w + ct) * 5 + kk) * 64 + l) * 8);
      w1l_r[ct][kk] = *(const h8v*)(W1l + (((long)(2 * w + ct) * 5 + kk) * 64 + l) * 8);
    }
#pragma unroll
    for (int kk = 0; kk < 8; ++kk)
      w2h_r[ct][kk] = *(const h8v*)(W2h + (((long)(2 * w + ct) * 8 + kk) * 64 + l) * 8);
  }
#pragma unroll
  for (int kk = 0; kk < 5; ++kk) {
    rwh_r[kk] = *(const h8v*)(rWh + (((long)w * 5 + kk) * 64 + l) * 8);
    rwl_r[kk] = *(const h8v*)(rWl + (((long)w * 5 + kk) * 64 + l) * 8);
  }
  // LDS: W3 pair (linear copy)
  for (int i = tid; i < 4096; i += 512) {
    ((h8v*)w3h_l)[i] = ((const h8v*)W3h)[i];
    ((h8v*)w3l_l)[i] = ((const h8v*)W3l)[i];
  }

  const float bbA = b1[(2 * w + 0) * 16 + c], bbB = b1[(2 * w + 1) * 16 + c];
  const float cbA = b2[(2 * w + 0) * 16 + c], cbB = b2[(2 * w + 1) * 16 + c];
  const float dB  = b3[w * 16 + c] + rb[w * 16 + c];

  // seed state f16 pair (cols 0..127 only)
  for (int idx = tid; idx < 2048; idx += 512) {
    int r = idx >> 7, cc = idx & 127;
    float x = xstate[(long)(b0 + r) * 128 + cc];
    _Float16 hi = (_Float16)x;
    xu_h[r][cc] = __builtin_bit_cast(unsigned short, hi);
    xu_l[r][cc] = f2h((x - (float)hi) * 2048.f);
  }
  // u fragment double-buffer: load u(t0) per-lane in fragment layout (g<2)
  float4 uc0, uc1;
  if (g < 2) {
    const float* up = ufut + ((long)(b0 + c) * 256 + t0) * 16 + g * 8;
    uc0 = *(const float4*)up;
    uc1 = *(const float4*)(up + 4);
  }
  __syncthreads();

  for (int tc = 0; tc < len; ++tc) {
    const int t = t0 + tc;
    // build u fragment (kk=4 of K=160: cols 128..143 = u, 144..159 = 0)
    h8v ah4 = zeroh8(), al4 = zeroh8();
    if (g < 2) {
      float uu[8] = {uc0.x, uc0.y, uc0.z, uc0.w, uc1.x, uc1.y, uc1.z, uc1.w};
#pragma unroll
      for (int q = 0; q < 8; ++q) {
        _Float16 hi = (_Float16)uu[q];
        ah4[q] = hi;
        al4[q] = (_Float16)((uu[q] - (float)hi) * 2048.f);
      }
    }
    // prefetch u(t+1) (consumed next step; full step of slack)
    if (g < 2) {
      const int tt = (tc + 1 < len) ? (t + 1) : t;
      const float* up = ufut + ((long)(b0 + c) * 256 + tt) * 16 + g * 8;
      uc0 = *(const float4*)up;
      uc1 = *(const float4*)(up + 4);
    }
    // rolling W2lo: preload ct0
    h8v w2s[8];
#pragma unroll
    for (int kk = 0; kk < 8; ++kk)
      w2s[kk] = *(const h8v*)(W2l + (((long)(2 * w + 0) * 8 + kk) * 64 + l) * 8);
    // xf store — xu cols 0..127 stable since prev state-write barrier;
    // overlaps G1 compute, drain lands on barrier-1 under MFMA work
    {
      int r = tid >> 5, cc0 = (tid & 31) * 4;
      long row = ((long)(b0 + r) * len + tc) * 128 + cc0;
      unsigned long long ph = *(const unsigned long long*)(&xu_h[r][cc0]);
      unsigned long long pl = *(const unsigned long long*)(&xu_l[r][cc0]);
      *(unsigned long long*)(xfh + row) = ph;
      *(unsigned long long*)(xfl + row) = pl;
    }
    // GEMM1: xu pair x W1 pair -> h1 pair (kk<4 from LDS, kk=4 from regs)
    float v1s[2][4];
    {
      f4v t10 = zero4(), tl0 = zero4(), t11 = zero4(), tl1 = zero4();
#pragma unroll
      for (int kk = 0; kk < 5; ++kk) {
        h8v ah, al;
        if (kk < 4) {
          ah = *(const h8v*)(&xu_h[c][kk * 32 + g * 8]);
          al = *(const h8v*)(&xu_l[c][kk * 32 + g * 8]);
        } else { ah = ah4; al = al4; }
        t10 = mfmaH(ah, w1h_r[0][kk], t10);
        tl0 = mfmaH(al, w1h_r[0][kk], tl0);
        tl0 = mfmaH(ah, w1l_r[0][kk], tl0);
        t11 = mfmaH(ah, w1h_r[1][kk], t11);
        tl1 = mfmaH(al, w1h_r[1][kk], tl1);
        tl1 = mfmaH(ah, w1l_r[1][kk], tl1);
      }
#pragma unroll
      for (int j = 0; j < 4; ++j) {
        v1s[0][j] = t10[j] + tl0[j] * 0x1p-11f + bbA;
        v1s[1][j] = t11[j] + tl1[j] * 0x1p-11f + bbB;
      }
    }
    // issue ct1's W2lo stream now (hidden under tanh + writes + barrier)
    h8v w2s1[8];
#pragma unroll
    for (int kk = 0; kk < 8; ++kk)
      w2s1[kk] = *(const h8v*)(W2l + (((long)(2 * w + 1) * 8 + kk) * 64 + l) * 8);
#pragma unroll
    for (int ct = 0; ct < 2; ++ct)
#pragma unroll
      for (int j = 0; j < 4; ++j) {
        float tv = tanhf_fast(v1s[ct][j]);
        _Float16 hi = (_Float16)tv;
        hh[g * 4 + j][(2 * w + ct) * 16 + c] = __builtin_bit_cast(unsigned short, hi);
        hl[g * 4 + j][(2 * w + ct) * 16 + c] = f2h((tv - (float)hi) * 2048.f);
      }
    __syncthreads();  // barrier 1: h1 ready (xf store drained under G1)
    // GEMM2: h1 pair x W2 pair (ct-interleaved, A-frags read once)
    float v2s[2][4];
    {
      f4v t10 = zero4(), tl0 = zero4(), t11 = zero4(), tl1 = zero4();
#pragma unroll
      for (int kk = 0; kk < 8; ++kk) {
        h8v ah = *(const h8v*)(&hh[c][kk * 32 + g * 8]);
        h8v al = *(const h8v*)(&hl[c][kk * 32 + g * 8]);
        t10 = mfmaH(ah, w2h_r[0][kk], t10);
        tl0 = mfmaH(al, w2h_r[0][kk], tl0);
        tl0 = mfmaH(ah, w2s[kk], tl0);
        t11 = mfmaH(ah, w2h_r[1][kk], t11);
        tl1 = mfmaH(al, w2h_r[1][kk], tl1);
        tl1 = mfmaH(ah, w2s1[kk], tl1);
      }
#pragma unroll
      for (int j = 0; j < 4; ++j) {
        v2s[0][j] = t10[j] + tl0[j] * 0x1p-11f + cbA;
        v2s[1][j] = t11[j] + tl1[j] * 0x1p-11f + cbB;
      }
    }
    __syncthreads();  // barrier 2: drain h1 reads before overwriting hh/hl
#pragma unroll
    for (int ct = 0; ct < 2; ++ct)
#pragma unroll
      for (int j = 0; j < 4; ++j) {
        float tv = tanhf_fast(v2s[ct][j]);
        _Float16 hi = (_Float16)tv;
        hh[g * 4 + j][(2 * w + ct) * 16 + c] = __builtin_bit_cast(unsigned short, hi);
        hl[g * 4 + j][(2 * w + ct) * 16 + c] = f2h((tv - (float)hi) * 2048.f);
      }
    __syncthreads();  // barrier 3: h2 ready
    // GEMM3: h2 pair x W3 pair (LDS) + xu pair x rW pair (regs; kk=4 = u frag)
    {
      f4v t1 = zero4(), tl = zero4();
#pragma unroll
      for (int kk = 0; kk < 8; ++kk) {
        h8v ah = *(const h8v*)(&hh[c][kk * 32 + g * 8]);
        h8v al = *(const h8v*)(&hl[c][kk * 32 + g * 8]);
        h8v bh = *(const h8v*)(&w3h_l[((w * 8 + kk) * 64 + l) * 8]);
        h8v bl = *(const h8v*)(&w3l_l[((w * 8 + kk) * 64 + l) * 8]);
        t1 = mfmaH(ah, bh, t1);
        tl = mfmaH(al, bh, tl);
        tl = mfmaH(ah, bl, tl);
      }
#pragma unroll
      for (int kk = 0; kk < 5; ++kk) {
        h8v ah, al;
        if (kk < 4) {
          ah = *(const h8v*)(&xu_h[c][kk * 32 + g * 8]);
          al = *(const h8v*)(&xu_l[c][kk * 32 + g * 8]);
        } else { ah = ah4; al = al4; }
        t1 = mfmaH(ah, rwh_r[kk], t1);
        tl = mfmaH(al, rwh_r[kk], tl);
        tl = mfmaH(ah, rwl_r[kk], tl);
      }
      __syncthreads();  // barrier 4: drain xu/hh reads before state overwrite
#pragma unroll
      for (int j = 0; j < 4; ++j) {
        float xn = t1[j] + tl[j] * 0x1p-11f + dB;
        _Float16 hi = (_Float16)xn;
        xu_h[g * 4 + j][w * 16 + c] = __builtin_bit_cast(unsigned short, hi);
        xu_l[g * 4 + j][w * 16 + c] = f2h((xn - (float)hi) * 2048.f);
      }
    }
    __syncthreads();  // barrier 5: state ready
  }
  // chunk-final state writeback (fp32 = hi + lo*2^-11, exact)
  for (int idx = tid; idx < 2048; idx += 512) {
    int r = idx >> 7, cc = idx & 127;
    xstate[(long)(b0 + r) * 128 + cc] = h2f(xu_h[r][cc]) + h2f(xu_l[r][cc]) * 0x1p-11f;
  }
}

// ---------------- output network h (xf pair x f16-single weights) ------------
__global__ __launch_bounds__(512, 2)
void hnet_kernel(const unsigned short* __restrict__ xfh, const unsigned short* __restrict__ xfl,
                 const unsigned short* __restrict__ W1, const unsigned short* __restrict__ W2,
                 const unsigned short* __restrict__ W3, const unsigned short* __restrict__ rW,
                 const float* __restrict__ b1, const float* __restrict__ b2,
                 const float* __restrict__ b3, const float* __restrict__ rb,
                 float* __restrict__ out, int t0, int len) {
  __shared__ __align__(16) unsigned short h1[64][264];
  __shared__ __align__(16) unsigned short h2[64][264];
  __shared__ float part[4][16][16];
  const int tid = threadIdx.x;
  const int w = tid >> 6, l = tid & 63;
  const int c = l & 15, g = l >> 4;
  const long row0 = (long)blockIdx.x * 64;

  {  // stage A: h1 = tanh(xf(pair) @ W1 + b1)
    h8v w1f[2][4];
#pragma unroll
    for (int ct = 0; ct < 2; ++ct)
#pragma unroll
      for (int kk = 0; kk < 4; ++kk)
        w1f[ct][kk] = *(const h8v*)(W1 + (((long)(2 * w + ct) * 4 + kk) * 64 + l) * 8);
    const float bbA = b1[(2 * w + 0) * 16 + c], bbB = b1[(2 * w + 1) * 16 + c];
#pragma unroll
    for (int rt = 0; rt < 4; ++rt) {
      f4v t10 = zero4(), tl0 = zero4(), t11 = zero4(), tl1 = zero4();
#pragma unroll
      for (int kk = 0; kk < 4; ++kk) {
        h8v ah = *(const h8v*)(xfh + (row0 + rt * 16 + c) * 128 + kk * 32 + g * 8);
        h8v al = *(const h8v*)(xfl + (row0 + rt * 16 + c) * 128 + kk * 32 + g * 8);
        t10 = mfmaH(ah, w1f[0][kk], t10);
        tl0 = mfmaH(al, w1f[0][kk], tl0);
        t11 = mfmaH(ah, w1f[1][kk], t11);
        tl1 = mfmaH(al, w1f[1][kk], tl1);
      }
#pragma unroll
      for (int j = 0; j < 4; ++j) {
        h1[rt * 16 + g * 4 + j][(2 * w + 0) * 16 + c] =
            f2h(tanhf_fast(t10[j] + tl0[j] * 0x1p-11f + bbA));
        h1[rt * 16 + g * 4 + j][(2 * w + 1) * 16 + c] =
            f2h(tanhf_fast(t11[j] + tl1[j] * 0x1p-11f + bbB));
      }
    }
  }
  __syncthreads();
  {  // stage B: h2 = tanh(h1 @ W2 + b2), f16 single
    h8v w2f[2][8];
#pragma unroll
    for (int ct = 0; ct < 2; ++ct)
#pragma unroll
      for (int kk = 0; kk < 8; ++kk)
        w2f[ct][kk] = *(const h8v*)(W2 + (((long)(2 * w + ct) * 8 + kk) * 64 + l) * 8);
    const float bbA = b2[(2 * w + 0) * 16 + c], bbB = b2[(2 * w + 1) * 16 + c];
#pragma unroll
    for (int rt = 0; rt < 4; ++rt) {
      f4v a0 = zero4(), a1 = zero4();
#pragma unroll
      for (int kk = 0; kk < 8; ++kk) {
        h8v a = *(const h8v*)(&h1[rt * 16 + c][kk * 32 + g * 8]);
        a0 = mfmaH(a, w2f[0][kk], a0);
        a1 = mfmaH(a, w2f[1][kk], a1);
      }
#pragma unroll
      for (int j = 0; j < 4; ++j) {
        h2[rt * 16 + g * 4 + j][(2 * w + 0) * 16 + c] = f2h(tanhf_fast(a0[j] + bbA));
        h2[rt * 16 + g * 4 + j][(2 * w + 1) * 16 + c] = f2h(tanhf_fast(a1[j] + bbB));
      }
    }
  }
  __syncthreads();
  {  // stage C: y = h2 @ W3 + xf(pair) @ rW + b3 + rb
    const int rt = w & 3, kh = w >> 2;
    f4v t1 = zero4(), tl = zero4();
#pragma unroll
    for (int kk = 0; kk < 4; ++kk) {
      const int kkg = kh * 4 + kk;
      h8v a = *(const h8v*)(&h2[rt * 16 + c][kkg * 32 + g * 8]);
      h8v b = *(const h8v*)(W3 + ((long)(kkg * 64 + l)) * 8);
      t1 = mfmaH(a, b, t1);
    }
#pragma unroll
    for (int kk = 0; kk < 2; ++kk) {
      const int kkg = kh * 2 + kk;
      h8v ah = *(const h8v*)(xfh + (row0 + rt * 16 + c) * 128 + kkg * 32 + g * 8);
      h8v al = *(const h8v*)(xfl + (row0 + rt * 16 + c) * 128 + kkg * 32 + g * 8);
      h8v b = *(const h8v*)(rW + ((long)(kkg * 64 + l)) * 8);
      t1 = mfmaH(ah, b, t1);
      tl = mfmaH(al, b, tl);
    }
    float val[4];
#pragma unroll
    for (int j = 0; j < 4; ++j) val[j] = t1[j] + tl[j] * 0x1p-11f;
    if (w >= 4) {
#pragma unroll
      for (int j = 0; j < 4; ++j) part[rt][g * 4 + j][c] = val[j];
    }
    __syncthreads();
    if (w < 4) {
      const float bias = b3[c] + rb[c];
#pragma unroll
      for (int j = 0; j < 4; ++j) {
        const long grow = row0 + rt * 16 + g * 4 + j;
        const long bq = grow / len;
        const int tq = (int)(grow - bq * len);
        out[(bq * 256 + (t0 + tq)) * 16 + c] = val[j] + part[rt][g * 4 + j][c] + bias;
      }
    }
  }
}

// ---------------- host -------------------------------------------------------
extern "C" void kernel_launch(void* const* d_in, const int* in_sizes, int n_in,
                              void* d_out, int out_size, void* d_ws, size_t ws_size,
                              hipStream_t stream) {
  (void)in_sizes; (void)n_in; (void)out_size;
  const float* upast = (const float*)d_in[0];
  const float* ypast = (const float*)d_in[1];
  const float* ufut  = (const float*)d_in[2];
  const float* e_rW = (const float*)d_in[3];
  const float* e_rb = (const float*)d_in[4];
  const float* e_W1 = (const float*)d_in[5];
  const float* e_b1 = (const float*)d_in[6];
  const float* e_W2 = (const float*)d_in[7];
  const float* e_b2 = (const float*)d_in[8];
  const float* e_W3 = (const float*)d_in[9];
  const float* e_b3 = (const float*)d_in[10];
  const float* f_rW = (const float*)d_in[11];
  const float* f_rb = (const float*)d_in[12];
  const float* f_W1 = (const float*)d_in[13];
  const float* f_b1 = (const float*)d_in[14];
  const float* f_W2 = (const float*)d_in[15];
  const float* f_b2 = (const float*)d_in[16];
  const float* f_W3 = (const float*)d_in[17];
  const float* f_b3 = (const float*)d_in[18];
  const float* h_rW = (const float*)d_in[19];
  const float* h_rb = (const float*)d_in[20];
  const float* h_W1 = (const float*)d_in[21];
  const float* h_b1 = (const float*)d_in[22];
  const float* h_W2 = (const float*)d_in[23];
  const float* h_b2 = (const float*)d_in[24];
  const float* h_W3 = (const float*)d_in[25];
  const float* h_b3 = (const float*)d_in[26];
  float* out = (float*)d_out;

  // swizzle table: e_* bf16 pair (mode0), f_* f16 pair (mode3), h_* f16 (mode1)
  const float* srcs[12] = { e_W1, e_W2, e_W3, e_rW, f_W1, f_W2, f_W3, f_rW,
                            h_W1, h_W2, h_W3, h_rW };
  const int Ks [12] = {1024, 256, 256, 1024, 144, 256, 256, 144, 128, 256, 256, 128};
  const int Kps[12] = {1024, 256, 256, 1024, 160, 256, 256, 160, 128, 256, 256, 128};
  const int Ns [12] = { 256, 256, 128,  128, 256, 256, 128, 128, 256, 256,  16,  16};
  const int modes[12] = {0,0,0,0, 3,3,3,3, 1,1,1,1};

  SwzTable tbl;
  long woff = 0, offs[12];
  for (int i = 0; i < 12; ++i) { offs[i] = woff; woff += (long)Kps[i] * Ns[i]; }
  const long EA = offs[4];              // e-region elems
  const long FB = 2 * EA;
  const long EB = offs[8] - offs[4];    // f-region elems
  const long HB = FB + 2 * EB;
  for (int i = 0; i < 12; ++i) {
    tbl.d[i].src = srcs[i]; tbl.d[i].woff = offs[i];
    tbl.d[i].K = Ks[i]; tbl.d[i].Kp = Kps[i]; tbl.d[i].N = Ns[i]; tbl.d[i].mode = modes[i];
    if (modes[i] == 0)      { tbl.d[i].dhi = offs[i];              tbl.d[i].dlo = EA + offs[i]; }
    else if (modes[i] == 3) { long lo = offs[i] - offs[4];
                              tbl.d[i].dhi = FB + lo;              tbl.d[i].dlo = FB + EB + lo; }
    else                    { long lo = offs[i] - offs[8];
                              tbl.d[i].dhi = HB + lo;              tbl.d[i].dlo = 0; }
  }
  tbl.tot_work = woff;

  unsigned short* wswz = (unsigned short*)d_ws;
  const long WSHORTS = HB + (offs[11] - offs[8]) + (long)Kps[11] * Ns[11];
  const size_t XOFF = ((size_t)WSHORTS * 2 + 4095) & ~(size_t)4095;
  float* xstate = (float*)((char*)d_ws + XOFF);
  const size_t XF0 = XOFF + (2u << 20);
  int c = 64;
  {
    long cmax = ((long)ws_size - (long)XF0) >> 21;  // 2 MB per time-step (pair)
    if (cmax < c) c = (int)cmax;
    if (c < 1) c = 1;
  }
  unsigned short* xfh = (unsigned short*)((char*)d_ws + XF0);
  unsigned short* xfl = (unsigned short*)((char*)d_ws + XF0 + (size_t)c * 1048576);

  // kernel weight pointers
  const unsigned short* eW1h = wswz + offs[0];          const unsigned short* eW1l = wswz + EA + offs[0];
  const unsigned short* eW2h = wswz + offs[1];          const unsigned short* eW2l = wswz + EA + offs[1];
  const unsigned short* eW3h = wswz + offs[2];          const unsigned short* eW3l = wswz + EA + offs[2];
  const unsigned short* erWh = wswz + offs[3];          const unsigned short* erWl = wswz + EA + offs[3];
  const unsigned short* fW1h = wswz + FB + 0;           const unsigned short* fW1l = wswz + FB + EB + 0;
  const unsigned short* fW2h = wswz + FB + 40960;       const unsigned short* fW2l = wswz + FB + EB + 40960;
  const unsigned short* fW3h = wswz + FB + 106496;      const unsigned short* fW3l = wswz + FB + EB + 106496;
  const unsigned short* frWh = wswz + FB + 139264;      const unsigned short* frWl = wswz + FB + EB + 139264;
  const unsigned short* hW1 = wswz + HB + 0;
  const unsigned short* hW2 = wswz + HB + 32768;
  const unsigned short* hW3 = wswz + HB + 98304;
  const unsigned short* hrW = wswz + HB + 102400;

  swz_kernel<<<(int)((tbl.tot_work + 255) / 256), 256, 0, stream>>>(tbl, wswz);
  enc_kernel<<<256, 512, 0, stream>>>(upast, ypast,
                                      eW1h, eW1l, eW2h, eW2l, eW3h, eW3l, erWh, erWl,
                                      e_b1, e_b2, e_b3, e_rb, xstate);
  for (int t0 = 0; t0 < 256; t0 += c) {
    int len = 256 - t0; if (len > c) len = c;
    recur_kernel<<<256, 512, 0, stream>>>(ufut, fW1h, fW1l, fW2h, fW2l, fW3h, fW3l,
                                          frWh, frWl, f_b1, f_b2, f_b3, f_rb,
                                          xstate, xfh, xfl, t0, len);
    hnet_kernel<<<64 * len, 512, 0, stream>>>(xfh, xfl, hW1, hW2, hW3, hrW,
                                              h_b1, h_b2, h_b3, h_rb, out, t0, len);
  }
}

// Round 15
// 2857.354 us; speedup vs baseline: 1.1221x; 1.1221x over previous
//
#include <hip/hip_runtime.h>
#include <stdint.h>

// SUBNET_15290083574166: encoder MLP -> 256-step recurrent f MLP -> output h MLP
// B=4096, T=256, NX=128, NU=16, NY=16, NB=NA=32, H=256
//
// Precision (VERIFIED r4-r14, absmax 0.0625 vs thr 0.24): f16 hi/lo pairs
// (2^-22) on all recurrence operands, 2-accum (hi + lo*2^-11); encoder bf16
// pairs; hnet xf-pair x f16-single. DO NOT change the numerics.
//
// r15 = byte-identical revert to r13 (best measured: 2860us total, recur
// 568us). r14's u-frag-in-regs regressed (FETCH 150->605MB: cross-phase reg
// liveness tipped the 128-VGPR cliff -> weight rematerialization). The r13
// structure is the measured optimum over 15 variants:
//  - recur: r4 placement (184 declared regs, compiler AGPR-stash, 512thr,
//    VGPR_Count=128, FETCH 150MB) + scalar-u prefetch + deferred xf store
//  - hnet: r4 4096-block version
//  - plateau is structural: allocator 128-VGPR cliff, 160KB LDS wall,
//    serial 256-step chain (MfmaUtil 19% != hardware roofline)

typedef __attribute__((ext_vector_type(8))) short s8v;      // 8 bf16 bits
typedef __attribute__((ext_vector_type(8))) _Float16 h8v;   // 8 f16
typedef __attribute__((ext_vector_type(4))) float f4v;

__device__ __forceinline__ f4v mfma16(s8v a, s8v b, f4v c) {
  return __builtin_amdgcn_mfma_f32_16x16x32_bf16(a, b, c, 0, 0, 0);
}
__device__ __forceinline__ f4v mfmaH(h8v a, h8v b, f4v c) {
  return __builtin_amdgcn_mfma_f32_16x16x32_f16(a, b, c, 0, 0, 0);
}
__device__ __forceinline__ f4v zero4() { return (f4v){0.f, 0.f, 0.f, 0.f}; }

__device__ __forceinline__ unsigned short f2b(float x) {  // f32->bf16 RNE
  unsigned int u = __builtin_bit_cast(unsigned int, x);
  u += 0x7fffu + ((u >> 16) & 1u);
  return (unsigned short)(u >> 16);
}
__device__ __forceinline__ float b2f(unsigned short h) {
  return __builtin_bit_cast(float, (unsigned int)h << 16);
}
__device__ __forceinline__ unsigned short f2h(float x) {
  return __builtin_bit_cast(unsigned short, (_Float16)x);
}
__device__ __forceinline__ float h2f(unsigned short h) {
  return (float)__builtin_bit_cast(_Float16, h);
}

__device__ __forceinline__ float tanhf_fast(float x) {
  x = fminf(15.f, fmaxf(-15.f, x));
  float e = __expf(2.f * x);
  return (e - 1.f) / (e + 1.f);
}

// ---------------- weight swizzle: fp32 [K][N] -> fragment order ---------------
// frag: idx(nt,kk,lane,j) = ((nt*KK + kk)*64 + lane)*8 + j
//   holds W[kk*32 + (lane>>4)*8 + j][nt*16 + (lane&15)]  (zero-pad k>=K)
// mode 0: bf16 hi at dst[dhi+local], bf16 lo at dst[dlo+local]
// mode 3: f16 hi at dst[dhi+local], f16((v-hi)*2048) at dst[dlo+local]
// mode 1: f16 at dst[dhi+local]
struct SwzDesc { const float* src; long woff; long dhi; long dlo; int K; int Kp; int N; int mode; };
struct SwzTable { SwzDesc d[12]; long tot_work; };

__global__ void swz_kernel(SwzTable tbl, unsigned short* __restrict__ dst) {
  long gid = (long)blockIdx.x * 256 + threadIdx.x;
  if (gid >= tbl.tot_work) return;
  int i = 11;
  while (i > 0 && gid < tbl.d[i].woff) --i;
  const SwzDesc m = tbl.d[i];
  long local = gid - m.woff;
  int j = (int)(local & 7);
  int lane = (int)((local >> 3) & 63);
  long rem = local >> 9;
  int KK = m.Kp >> 5;
  int kk = (int)(rem % KK);
  int nt = (int)(rem / KK);
  int k = kk * 32 + (lane >> 4) * 8 + j;
  int n = nt * 16 + (lane & 15);
  float v = (k < m.K) ? m.src[(long)k * m.N + n] : 0.f;
  if (m.mode == 0) {
    unsigned short hi = f2b(v);
    dst[m.dhi + local] = hi;
    dst[m.dlo + local] = f2b(v - b2f(hi));
  } else if (m.mode == 3) {
    _Float16 hi = (_Float16)v;
    dst[m.dhi + local] = __builtin_bit_cast(unsigned short, hi);
    dst[m.dlo + local] = f2h((v - (float)hi) * 2048.f);
  } else {
    dst[m.dhi + local] = f2h(v);
  }
}

// ---------------- encoder (bf16 hi/lo 3-term, one-shot) ----------------------
__global__ __launch_bounds__(512, 2)
void enc_kernel(const float* __restrict__ upast, const float* __restrict__ ypast,
                const unsigned short* __restrict__ W1h, const unsigned short* __restrict__ W1l,
                const unsigned short* __restrict__ W2h, const unsigned short* __restrict__ W2l,
                const unsigned short* __restrict__ W3h, const unsigned short* __restrict__ W3l,
                const unsigned short* __restrict__ rWh, const unsigned short* __restrict__ rWl,
                const float* __restrict__ b1, const float* __restrict__ b2,
                const float* __restrict__ b3, const float* __restrict__ rb,
                float* __restrict__ xstate) {
  __shared__ __align__(16) unsigned short h1h[16][264], h1l[16][264];
  __shared__ __align__(16) unsigned short h2h[16][264], h2l[16][264];
  const int tid = threadIdx.x;
  const int w = tid >> 6, l = tid & 63;
  const int c = l & 15, g = l >> 4;
  const int b0 = blockIdx.x << 4;
  const long zrow = (long)(b0 + c) * 512;

  f4v a0 = zero4(), a1 = zero4();
  for (int kk = 0; kk < 32; ++kk) {
    const int cb = kk * 32 + g * 8;
    const float* zp = (cb < 512) ? (upast + zrow + cb) : (ypast + zrow + (cb - 512));
    float4 z0 = *(const float4*)zp;
    float4 z1 = *(const float4*)(zp + 4);
    float zz[8] = {z0.x, z0.y, z0.z, z0.w, z1.x, z1.y, z1.z, z1.w};
    s8v ah, al;
#pragma unroll
    for (int q = 0; q < 8; ++q) {
      unsigned short hi = f2b(zz[q]);
      ah[q] = (short)hi; al[q] = (short)f2b(zz[q] - b2f(hi));
    }
#pragma unroll
    for (int ct = 0; ct < 2; ++ct) {
      s8v bh = *(const s8v*)(W1h + (((long)(2 * w + ct) * 32 + kk) * 64 + l) * 8);
      s8v bl = *(const s8v*)(W1l + (((long)(2 * w + ct) * 32 + kk) * 64 + l) * 8);
      f4v& acc = ct ? a1 : a0;
      acc = mfma16(ah, bh, acc);
      acc = mfma16(al, bh, acc);
      acc = mfma16(ah, bl, acc);
    }
  }
  {
    const float bbA = b1[(2 * w + 0) * 16 + c], bbB = b1[(2 * w + 1) * 16 + c];
#pragma unroll
    for (int j = 0; j < 4; ++j) {
      float tA = tanhf_fast(a0[j] + bbA), tB = tanhf_fast(a1[j] + bbB);
      unsigned short hA = f2b(tA), hB = f2b(tB);
      h1h[g * 4 + j][(2 * w + 0) * 16 + c] = hA;
      h1l[g * 4 + j][(2 * w + 0) * 16 + c] = f2b(tA - b2f(hA));
      h1h[g * 4 + j][(2 * w + 1) * 16 + c] = hB;
      h1l[g * 4 + j][(2 * w + 1) * 16 + c] = f2b(tB - b2f(hB));
    }
  }
  __syncthreads();
  a0 = zero4(); a1 = zero4();
#pragma unroll
  for (int kk = 0; kk < 8; ++kk) {
    s8v ah = *(const s8v*)(&h1h[c][kk * 32 + g * 8]);
    s8v al = *(const s8v*)(&h1l[c][kk * 32 + g * 8]);
#pragma unroll
    for (int ct = 0; ct < 2; ++ct) {
      s8v bh = *(const s8v*)(W2h + (((long)(2 * w + ct) * 8 + kk) * 64 + l) * 8);
      s8v bl = *(const s8v*)(W2l + (((long)(2 * w + ct) * 8 + kk) * 64 + l) * 8);
      f4v& acc = ct ? a1 : a0;
      acc = mfma16(ah, bh, acc);
      acc = mfma16(al, bh, acc);
      acc = mfma16(ah, bl, acc);
    }
  }
  {
    const float bbA = b2[(2 * w + 0) * 16 + c], bbB = b2[(2 * w + 1) * 16 + c];
#pragma unroll
    for (int j = 0; j < 4; ++j) {
      float tA = tanhf_fast(a0[j] + bbA), tB = tanhf_fast(a1[j] + bbB);
      unsigned short hA = f2b(tA), hB = f2b(tB);
      h2h[g * 4 + j][(2 * w + 0) * 16 + c] = hA;
      h2l[g * 4 + j][(2 * w + 0) * 16 + c] = f2b(tA - b2f(hA));
      h2h[g * 4 + j][(2 * w + 1) * 16 + c] = hB;
      h2l[g * 4 + j][(2 * w + 1) * 16 + c] = f2b(tB - b2f(hB));
    }
  }
  __syncthreads();
  f4v ac = zero4();
#pragma unroll
  for (int kk = 0; kk < 8; ++kk) {
    s8v ah = *(const s8v*)(&h2h[c][kk * 32 + g * 8]);
    s8v al = *(const s8v*)(&h2l[c][kk * 32 + g * 8]);
    s8v bh = *(const s8v*)(W3h + (((long)w * 8 + kk) * 64 + l) * 8);
    s8v bl = *(const s8v*)(W3l + (((long)w * 8 + kk) * 64 + l) * 8);
    ac = mfma16(ah, bh, ac);
    ac = mfma16(al, bh, ac);
    ac = mfma16(ah, bl, ac);
  }
  for (int kk = 0; kk < 32; ++kk) {
    const int cb = kk * 32 + g * 8;
    const float* zp = (cb < 512) ? (upast + zrow + cb) : (ypast + zrow + (cb - 512));
    float4 z0 = *(const float4*)zp;
    float4 z1 = *(const float4*)(zp + 4);
    float zz[8] = {z0.x, z0.y, z0.z, z0.w, z1.x, z1.y, z1.z, z1.w};
    s8v ah, al;
#pragma unroll
    for (int q = 0; q < 8; ++q) {
      unsigned short hi = f2b(zz[q]);
      ah[q] = (short)hi; al[q] = (short)f2b(zz[q] - b2f(hi));
    }
    s8v bh = *(const s8v*)(rWh + (((long)w * 32 + kk) * 64 + l) * 8);
    s8v bl = *(const s8v*)(rWl + (((long)w * 32 + kk) * 64 + l) * 8);
    ac = mfma16(ah, bh, ac);
    ac = mfma16(al, bh, ac);
    ac = mfma16(ah, bl, ac);
  }
  {
    const float bias = b3[w * 16 + c] + rb[w * 16 + c];
#pragma unroll
    for (int j = 0; j < 4; ++j)
      xstate[(long)(b0 + g * 4 + j) * 128 + w * 16 + c] = ac[j] + bias;
  }
}

// ---------------- recurrence (f16 pairs, u-prefetch + deferred xf store) -----
// regs persistent (184): W1 pair 80, W2hi 64, rW pair 40. LDS: W3 pair 128KB +
// activations ~27KB. W2lo streamed from L2 (ct0 preload, ct1 in G1 tail).
__global__ __launch_bounds__(512, 2)
void recur_kernel(const float* __restrict__ ufut,
                  const unsigned short* __restrict__ W1h, const unsigned short* __restrict__ W1l,
                  const unsigned short* __restrict__ W2h, const unsigned short* __restrict__ W2l,
                  const unsigned short* __restrict__ W3h, const unsigned short* __restrict__ W3l,
                  const unsigned short* __restrict__ rWh, const unsigned short* __restrict__ rWl,
                  const float* __restrict__ b1, const float* __restrict__ b2,
                  const float* __restrict__ b3, const float* __restrict__ rb,
                  float* __restrict__ xstate,
                  unsigned short* __restrict__ xfh, unsigned short* __restrict__ xfl,
                  int t0, int len) {
  __shared__ __align__(16) unsigned short xu_h[16][168], xu_l[16][168];
  __shared__ __align__(16) unsigned short hh[16][264], hl[16][264];
  __shared__ __align__(16) unsigned short w3h_l[32768];   // W3 hi, full
  __shared__ __align__(16) unsigned short w3l_l[32768];   // W3 lo, full
  const int tid = threadIdx.x;
  const int w = tid >> 6, l = tid & 63;
  const int c = l & 15, g = l >> 4;
  const int b0 = blockIdx.x << 4;

  // persistent register fragments (f16)
  h8v w1h_r[2][5], w1l_r[2][5], w2h_r[2][8], rwh_r[5], rwl_r[5];
#pragma unroll
  for (int ct = 0; ct < 2; ++ct) {
#pragma unroll
    for (int kk = 0; kk < 5; ++kk) {
      w1h_r[ct][kk] = *(const h8v*)(W1h + (((long)(2 * w + ct) * 5 + kk) * 64 + l) * 8);
      w1l_r[ct][kk] = *(const h8v*)(W1l + (((long)(2 * w + ct) * 5 + kk) * 64 + l) * 8);
    }
#pragma unroll
    for (int kk = 0; kk < 8; ++kk)
      w2h_r[ct][kk] = *(const h8v*)(W2h + (((long)(2 * w + ct) * 8 + kk) * 64 + l) * 8);
  }
#pragma unroll
  for (int kk = 0; kk < 5; ++kk) {
    rwh_r[kk] = *(const h8v*)(rWh + (((long)w * 5 + kk) * 64 + l) * 8);
    rwl_r[kk] = *(const h8v*)(rWl + (((long)w * 5 + kk) * 64 + l) * 8);
  }
  // LDS: W3 pair (linear copy)
  for (int i = tid; i < 4096; i += 512) {
    ((h8v*)w3h_l)[i] = ((const h8v*)W3h)[i];
    ((h8v*)w3l_l)[i] = ((const h8v*)W3l)[i];
  }

  const float bbA = b1[(2 * w + 0) * 16 + c], bbB = b1[(2 * w + 1) * 16 + c];
  const float cbA = b2[(2 * w + 0) * 16 + c], cbB = b2[(2 * w + 1) * 16 + c];
  const float dB  = b3[w * 16 + c] + rb[w * 16 + c];

  // seed state f16 pair; zero k-pad cols 144..167
  for (int idx = tid; idx < 2048; idx += 512) {
    int r = idx >> 7, cc = idx & 127;
    float x = xstate[(long)(b0 + r) * 128 + cc];
    _Float16 hi = (_Float16)x;
    xu_h[r][cc] = __builtin_bit_cast(unsigned short, hi);
    xu_l[r][cc] = f2h((x - (float)hi) * 2048.f);
  }
  for (int idx = tid; idx < 16 * 24; idx += 512) {
    int r = idx / 24, cc = 144 + (idx % 24);
    xu_h[r][cc] = 0; xu_l[r][cc] = 0;
  }
  // u-prefetch: load u(t0) into regs (tid<256: 1 value each)
  const int ur = tid >> 4, uc = tid & 15;
  float uval = 0.f;
  if (tid < 256) uval = ufut[((long)(b0 + ur) * 256 + t0) * 16 + uc];
  __syncthreads();

  for (int tc = 0; tc < len; ++tc) {
    const int t = t0 + tc;
    // rolling W2lo: preload ct0
    h8v w2s[8];
#pragma unroll
    for (int kk = 0; kk < 8; ++kk)
      w2s[kk] = *(const h8v*)(W2l + (((long)(2 * w + 0) * 8 + kk) * 64 + l) * 8);
    // phase 0 (short): u_t pair from prefetched reg into cols 128..143
    if (tid < 256) {
      _Float16 hi = (_Float16)uval;
      xu_h[ur][128 + uc] = __builtin_bit_cast(unsigned short, hi);
      xu_l[ur][128 + uc] = f2h((uval - (float)hi) * 2048.f);
    }
    __syncthreads();  // barrier 1: xu complete for this step
    // prefetch u(t+1) (consumed next step; ~full step of slack to land)
    if (tid < 256) {
      const int tt = (tc + 1 < len) ? (t + 1) : t;
      uval = ufut[((long)(b0 + ur) * 256 + tt) * 16 + uc];
    }
    // xf store — issued here so it overlaps G1 compute; xu stable until G3-end
    {
      int r = tid >> 5, cc0 = (tid & 31) * 4;
      long row = ((long)(b0 + r) * len + tc) * 128 + cc0;
      unsigned long long ph = *(const unsigned long long*)(&xu_h[r][cc0]);
      unsigned long long pl = *(const unsigned long long*)(&xu_l[r][cc0]);
      *(unsigned long long*)(xfh + row) = ph;
      *(unsigned long long*)(xfl + row) = pl;
    }
    // GEMM1: xu pair x W1 pair -> h1 pair
    float v1s[2][4];
    {
      f4v t10 = zero4(), tl0 = zero4(), t11 = zero4(), tl1 = zero4();
#pragma unroll
      for (int kk = 0; kk < 5; ++kk) {
        h8v ah = *(const h8v*)(&xu_h[c][kk * 32 + g * 8]);
        h8v al = *(const h8v*)(&xu_l[c][kk * 32 + g * 8]);
        t10 = mfmaH(ah, w1h_r[0][kk], t10);
        tl0 = mfmaH(al, w1h_r[0][kk], tl0);
        tl0 = mfmaH(ah, w1l_r[0][kk], tl0);
        t11 = mfmaH(ah, w1h_r[1][kk], t11);
        tl1 = mfmaH(al, w1h_r[1][kk], tl1);
        tl1 = mfmaH(ah, w1l_r[1][kk], tl1);
      }
#pragma unroll
      for (int j = 0; j < 4; ++j) {
        v1s[0][j] = t10[j] + tl0[j] * 0x1p-11f + bbA;
        v1s[1][j] = t11[j] + tl1[j] * 0x1p-11f + bbB;
      }
    }
    // issue ct1's W2lo stream now (hidden under tanh + writes + barrier)
    h8v w2s1[8];
#pragma unroll
    for (int kk = 0; kk < 8; ++kk)
      w2s1[kk] = *(const h8v*)(W2l + (((long)(2 * w + 1) * 8 + kk) * 64 + l) * 8);
#pragma unroll
    for (int ct = 0; ct < 2; ++ct)
#pragma unroll
      for (int j = 0; j < 4; ++j) {
        float tv = tanhf_fast(v1s[ct][j]);
        _Float16 hi = (_Float16)tv;
        hh[g * 4 + j][(2 * w + ct) * 16 + c] = __builtin_bit_cast(unsigned short, hi);
        hl[g * 4 + j][(2 * w + ct) * 16 + c] = f2h((tv - (float)hi) * 2048.f);
      }
    __syncthreads();  // barrier 2: h1 ready (also drains xf store under G1 work)
    // GEMM2: h1 pair x W2 pair (ct-interleaved, A-frags read once)
    float v2s[2][4];
    {
      f4v t10 = zero4(), tl0 = zero4(), t11 = zero4(), tl1 = zero4();
#pragma unroll
      for (int kk = 0; kk < 8; ++kk) {
        h8v ah = *(const h8v*)(&hh[c][kk * 32 + g * 8]);
        h8v al = *(const h8v*)(&hl[c][kk * 32 + g * 8]);
        t10 = mfmaH(ah, w2h_r[0][kk], t10);
        tl0 = mfmaH(al, w2h_r[0][kk], tl0);
        tl0 = mfmaH(ah, w2s[kk], tl0);
        t11 = mfmaH(ah, w2h_r[1][kk], t11);
        tl1 = mfmaH(al, w2h_r[1][kk], tl1);
        tl1 = mfmaH(ah, w2s1[kk], tl1);
      }
#pragma unroll
      for (int j = 0; j < 4; ++j) {
        v2s[0][j] = t10[j] + tl0[j] * 0x1p-11f + cbA;
        v2s[1][j] = t11[j] + tl1[j] * 0x1p-11f + cbB;
      }
    }
    __syncthreads();  // barrier 3: drain h1 reads before overwriting hh/hl
#pragma unroll
    for (int ct = 0; ct < 2; ++ct)
#pragma unroll
      for (int j = 0; j < 4; ++j) {
        float tv = tanhf_fast(v2s[ct][j]);
        _Float16 hi = (_Float16)tv;
        hh[g * 4 + j][(2 * w + ct) * 16 + c] = __builtin_bit_cast(unsigned short, hi);
        hl[g * 4 + j][(2 * w + ct) * 16 + c] = f2h((tv - (float)hi) * 2048.f);
      }
    __syncthreads();  // barrier 4: h2 ready
    // GEMM3: h2 pair x W3 pair (LDS) + xu pair x rW pair (regs)
    {
      f4v t1 = zero4(), tl = zero4();
#pragma unroll
      for (int kk = 0; kk < 8; ++kk) {
        h8v ah = *(const h8v*)(&hh[c][kk * 32 + g * 8]);
        h8v al = *(const h8v*)(&hl[c][kk * 32 + g * 8]);
        h8v bh = *(const h8v*)(&w3h_l[((w * 8 + kk) * 64 + l) * 8]);
        h8v bl = *(const h8v*)(&w3l_l[((w * 8 + kk) * 64 + l) * 8]);
        t1 = mfmaH(ah, bh, t1);
        tl = mfmaH(al, bh, tl);
        tl = mfmaH(ah, bl, tl);
      }
#pragma unroll
      for (int kk = 0; kk < 5; ++kk) {
        h8v ah = *(const h8v*)(&xu_h[c][kk * 32 + g * 8]);
        h8v al = *(const h8v*)(&xu_l[c][kk * 32 + g * 8]);
        t1 = mfmaH(ah, rwh_r[kk], t1);
        tl = mfmaH(al, rwh_r[kk], tl);
        tl = mfmaH(ah, rwl_r[kk], tl);
      }
      __syncthreads();  // barrier 5: drain xu/hh reads before state overwrite
#pragma unroll
      for (int j = 0; j < 4; ++j) {
        float xn = t1[j] + tl[j] * 0x1p-11f + dB;
        _Float16 hi = (_Float16)xn;
        xu_h[g * 4 + j][w * 16 + c] = __builtin_bit_cast(unsigned short, hi);
        xu_l[g * 4 + j][w * 16 + c] = f2h((xn - (float)hi) * 2048.f);
      }
    }
    __syncthreads();  // barrier 6: state ready
  }
  // chunk-final state writeback (fp32 = hi + lo*2^-11, exact)
  for (int idx = tid; idx < 2048; idx += 512) {
    int r = idx >> 7, cc = idx & 127;
    xstate[(long)(b0 + r) * 128 + cc] = h2f(xu_h[r][cc]) + h2f(xu_l[r][cc]) * 0x1p-11f;
  }
}

// ---------------- output network h (xf pair x f16-single weights) ------------
__global__ __launch_bounds__(512, 2)
void hnet_kernel(const unsigned short* __restrict__ xfh, const unsigned short* __restrict__ xfl,
                 const unsigned short* __restrict__ W1, const unsigned short* __restrict__ W2,
                 const unsigned short* __restrict__ W3, const unsigned short* __restrict__ rW,
                 const float* __restrict__ b1, const float* __restrict__ b2,
                 const float* __restrict__ b3, const float* __restrict__ rb,
                 float* __restrict__ out, int t0, int len) {
  __shared__ __align__(16) unsigned short h1[64][264];
  __shared__ __align__(16) unsigned short h2[64][264];
  __shared__ float part[4][16][16];
  const int tid = threadIdx.x;
  const int w = tid >> 6, l = tid & 63;
  const int c = l & 15, g = l >> 4;
  const long row0 = (long)blockIdx.x * 64;

  {  // stage A: h1 = tanh(xf(pair) @ W1 + b1)
    h8v w1f[2][4];
#pragma unroll
    for (int ct = 0; ct < 2; ++ct)
#pragma unroll
      for (int kk = 0; kk < 4; ++kk)
        w1f[ct][kk] = *(const h8v*)(W1 + (((long)(2 * w + ct) * 4 + kk) * 64 + l) * 8);
    const float bbA = b1[(2 * w + 0) * 16 + c], bbB = b1[(2 * w + 1) * 16 + c];
#pragma unroll
    for (int rt = 0; rt < 4; ++rt) {
      f4v t10 = zero4(), tl0 = zero4(), t11 = zero4(), tl1 = zero4();
#pragma unroll
      for (int kk = 0; kk < 4; ++kk) {
        h8v ah = *(const h8v*)(xfh + (row0 + rt * 16 + c) * 128 + kk * 32 + g * 8);
        h8v al = *(const h8v*)(xfl + (row0 + rt * 16 + c) * 128 + kk * 32 + g * 8);
        t10 = mfmaH(ah, w1f[0][kk], t10);
        tl0 = mfmaH(al, w1f[0][kk], tl0);
        t11 = mfmaH(ah, w1f[1][kk], t11);
        tl1 = mfmaH(al, w1f[1][kk], tl1);
      }
#pragma unroll
      for (int j = 0; j < 4; ++j) {
        h1[rt * 16 + g * 4 + j][(2 * w + 0) * 16 + c] =
            f2h(tanhf_fast(t10[j] + tl0[j] * 0x1p-11f + bbA));
        h1[rt * 16 + g * 4 + j][(2 * w + 1) * 16 + c] =
            f2h(tanhf_fast(t11[j] + tl1[j] * 0x1p-11f + bbB));
      }
    }
  }
  __syncthreads();
  {  // stage B: h2 = tanh(h1 @ W2 + b2), f16 single
    h8v w2f[2][8];
#pragma unroll
    for (int ct = 0; ct < 2; ++ct)
#pragma unroll
      for (int kk = 0; kk < 8; ++kk)
        w2f[ct][kk] = *(const h8v*)(W2 + (((long)(2 * w + ct) * 8 + kk) * 64 + l) * 8);
    const float bbA = b2[(2 * w + 0) * 16 + c], bbB = b2[(2 * w + 1) * 16 + c];
#pragma unroll
    for (int rt = 0; rt < 4; ++rt) {
      f4v a0 = zero4(), a1 = zero4();
#pragma unroll
      for (int kk = 0; kk < 8; ++kk) {
        h8v a = *(const h8v*)(&h1[rt * 16 + c][kk * 32 + g * 8]);
        a0 = mfmaH(a, w2f[0][kk], a0);
        a1 = mfmaH(a, w2f[1][kk], a1);
      }
#pragma unroll
      for (int j = 0; j < 4; ++j) {
        h2[rt * 16 + g * 4 + j][(2 * w + 0) * 16 + c] = f2h(tanhf_fast(a0[j] + bbA));
        h2[rt * 16 + g * 4 + j][(2 * w + 1) * 16 + c] = f2h(tanhf_fast(a1[j] + bbB));
      }
    }
  }
  __syncthreads();
  {  // stage C: y = h2 @ W3 + xf(pair) @ rW + b3 + rb
    const int rt = w & 3, kh = w >> 2;
    f4v t1 = zero4(), tl = zero4();
#pragma unroll
    for (int kk = 0; kk < 4; ++kk) {
      const int kkg = kh * 4 + kk;
      h8v a = *(const h8v*)(&h2[rt * 16 + c][kkg * 32 + g * 8]);
      h8v b = *(const h8v*)(W3 + ((long)(kkg * 64 + l)) * 8);
      t1 = mfmaH(a, b, t1);
    }
#pragma unroll
    for (int kk = 0; kk < 2; ++kk) {
      const int kkg = kh * 2 + kk;
      h8v ah = *(const h8v*)(xfh + (row0 + rt * 16 + c) * 128 + kkg * 32 + g * 8);
      h8v al = *(const h8v*)(xfl + (row0 + rt * 16 + c) * 128 + kkg * 32 + g * 8);
      h8v b = *(const h8v*)(rW + ((long)(kkg * 64 + l)) * 8);
      t1 = mfmaH(ah, b, t1);
      tl = mfmaH(al, b, tl);
    }
    float val[4];
#pragma unroll
    for (int j = 0; j < 4; ++j) val[j] = t1[j] + tl[j] * 0x1p-11f;
    if (w >= 4) {
#pragma unroll
      for (int j = 0; j < 4; ++j) part[rt][g * 4 + j][c] = val[j];
    }
    __syncthreads();
    if (w < 4) {
      const float bias = b3[c] + rb[c];
#pragma unroll
      for (int j = 0; j < 4; ++j) {
        const long grow = row0 + rt * 16 + g * 4 + j;
        const long bq = grow / len;
        const int tq = (int)(grow - bq * len);
        out[(bq * 256 + (t0 + tq)) * 16 + c] = val[j] + part[rt][g * 4 + j][c] + bias;
      }
    }
  }
}

// ---------------- host -------------------------------------------------------
extern "C" void kernel_launch(void* const* d_in, const int* in_sizes, int n_in,
                              void* d_out, int out_size, void* d_ws, size_t ws_size,
                              hipStream_t stream) {
  (void)in_sizes; (void)n_in; (void)out_size;
  const float* upast = (const float*)d_in[0];
  const float* ypast = (const float*)d_in[1];
  const float* ufut  = (const float*)d_in[2];
  const float* e_rW = (const float*)d_in[3];
  const float* e_rb = (const float*)d_in[4];
  const float* e_W1 = (const float*)d_in[5];
  const float* e_b1 = (const float*)d_in[6];
  const float* e_W2 = (const float*)d_in[7];
  const float* e_b2 = (const float*)d_in[8];
  const float* e_W3 = (const float*)d_in[9];
  const float* e_b3 = (const float*)d_in[10];
  const float* f_rW = (const float*)d_in[11];
  const float* f_rb = (const float*)d_in[12];
  const float* f_W1 = (const float*)d_in[13];
  const float* f_b1 = (const float*)d_in[14];
  const float* f_W2 = (const float*)d_in[15];
  const float* f_b2 = (const float*)d_in[16];
  const float* f_W3 = (const float*)d_in[17];
  const float* f_b3 = (const float*)d_in[18];
  const float* h_rW = (const float*)d_in[19];
  const float* h_rb = (const float*)d_in[20];
  const float* h_W1 = (const float*)d_in[21];
  const float* h_b1 = (const float*)d_in[22];
  const float* h_W2 = (const float*)d_in[23];
  const float* h_b2 = (const float*)d_in[24];
  const float* h_W3 = (const float*)d_in[25];
  const float* h_b3 = (const float*)d_in[26];
  float* out = (float*)d_out;

  // swizzle table: e_* bf16 pair (mode0), f_* f16 pair (mode3), h_* f16 (mode1)
  const float* srcs[12] = { e_W1, e_W2, e_W3, e_rW, f_W1, f_W2, f_W3, f_rW,
                            h_W1, h_W2, h_W3, h_rW };
  const int Ks [12] = {1024, 256, 256, 1024, 144, 256, 256, 144, 128, 256, 256, 128};
  const int Kps[12] = {1024, 256, 256, 1024, 160, 256, 256, 160, 128, 256, 256, 128};
  const int Ns [12] = { 256, 256, 128,  128, 256, 256, 128, 128, 256, 256,  16,  16};
  const int modes[12] = {0,0,0,0, 3,3,3,3, 1,1,1,1};

  SwzTable tbl;
  long woff = 0, offs[12];
  for (int i = 0; i < 12; ++i) { offs[i] = woff; woff += (long)Kps[i] * Ns[i]; }
  const long EA = offs[4];              // e-region elems
  const long FB = 2 * EA;
  const long EB = offs[8] - offs[4];    // f-region elems
  const long HB = FB + 2 * EB;
  for (int i = 0; i < 12; ++i) {
    tbl.d[i].src = srcs[i]; tbl.d[i].woff = offs[i];
    tbl.d[i].K = Ks[i]; tbl.d[i].Kp = Kps[i]; tbl.d[i].N = Ns[i]; tbl.d[i].mode = modes[i];
    if (modes[i] == 0)      { tbl.d[i].dhi = offs[i];              tbl.d[i].dlo = EA + offs[i]; }
    else if (modes[i] == 3) { long lo = offs[i] - offs[4];
                              tbl.d[i].dhi = FB + lo;              tbl.d[i].dlo = FB + EB + lo; }
    else                    { long lo = offs[i] - offs[8];
                              tbl.d[i].dhi = HB + lo;              tbl.d[i].dlo = 0; }
  }
  tbl.tot_work = woff;

  unsigned short* wswz = (unsigned short*)d_ws;
  const long WSHORTS = HB + (offs[11] - offs[8]) + (long)Kps[11] * Ns[11];
  const size_t XOFF = ((size_t)WSHORTS * 2 + 4095) & ~(size_t)4095;
  float* xstate = (float*)((char*)d_ws + XOFF);
  const size_t XF0 = XOFF + (2u << 20);
  int c = 64;
  {
    long cmax = ((long)ws_size - (long)XF0) >> 21;  // 2 MB per time-step (pair)
    if (cmax < c) c = (int)cmax;
    if (c < 1) c = 1;
  }
  unsigned short* xfh = (unsigned short*)((char*)d_ws + XF0);
  unsigned short* xfl = (unsigned short*)((char*)d_ws + XF0 + (size_t)c * 1048576);

  // kernel weight pointers
  const unsigned short* eW1h = wswz + offs[0];          const unsigned short* eW1l = wswz + EA + offs[0];
  const unsigned short* eW2h = wswz + offs[1];          const unsigned short* eW2l = wswz + EA + offs[1];
  const unsigned short* eW3h = wswz + offs[2];          const unsigned short* eW3l = wswz + EA + offs[2];
  const unsigned short* erWh = wswz + offs[3];          const unsigned short* erWl = wswz + EA + offs[3];
  const unsigned short* fW1h = wswz + FB + 0;           const unsigned short* fW1l = wswz + FB + EB + 0;
  const unsigned short* fW2h = wswz + FB + 40960;       const unsigned short* fW2l = wswz + FB + EB + 40960;
  const unsigned short* fW3h = wswz + FB + 106496;      const unsigned short* fW3l = wswz + FB + EB + 106496;
  const unsigned short* frWh = wswz + FB + 139264;      const unsigned short* frWl = wswz + FB + EB + 139264;
  const unsigned short* hW1 = wswz + HB + 0;
  const unsigned short* hW2 = wswz + HB + 32768;
  const unsigned short* hW3 = wswz + HB + 98304;
  const unsigned short* hrW = wswz + HB + 102400;

  swz_kernel<<<(int)((tbl.tot_work + 255) / 256), 256, 0, stream>>>(tbl, wswz);
  enc_kernel<<<256, 512, 0, stream>>>(upast, ypast,
                                      eW1h, eW1l, eW2h, eW2l, eW3h, eW3l, erWh, erWl,
                                      e_b1, e_b2, e_b3, e_rb, xstate);
  for (int t0 = 0; t0 < 256; t0 += c) {
    int len = 256 - t0; if (len > c) len = c;
    recur_kernel<<<256, 512, 0, stream>>>(ufut, fW1h, fW1l, fW2h, fW2l, fW3h, fW3l,
                                          frWh, frWl, f_b1, f_b2, f_b3, f_rb,
                                          xstate, xfh, xfl, t0, len);
    hnet_kernel<<<64 * len, 512, 0, stream>>>(xfh, xfl, hW1, hW2, hW3, hrW,
                                              h_b1, h_b2, h_b3, h_rb, out, t0, len);
  }
}